// Round 16
// baseline (176.880 us; speedup 1.0000x reference)
//
#include <hip/hip_runtime.h>
#include <cstdint>
#include <cstddef>

#define NPOS   15200
#define NANCH  136800
#define KDIM   1024
#define NCLS   18
#define NBB    36
#define KS     8
#define KCH    (KDIM / KS)        // 128 k per split
#define KSTEP  32
#define MTILE  128
#define WHALF  64                 // weights staged per half-chunk
#define MCAP   4096
#define NROW   2048               // NMS mask rows (processing depth cap; fallback beyond)
#define NWRD   32                 // mask words per row (2048 cols)
#define TARGET_SEL 3072
#define KSEL   1000
#define HBINS  8192
#define ZWORDS ((HBINS * 4 + 256 + MCAP * 4) / 4)

typedef unsigned long long u64;

// out layout (floats): proposals[1000*4] | idx[1000] | cls_prob[273600] | cls_pred[136800] | bbox_pred[547200]
#define OFF_PROP    0
#define OFF_IDX     4000
#define OFF_CLSPROB 5000
#define OFF_CLSPRED 278600
#define OFF_BB      415400

struct Ctrl {
  int selCount;
  int bstar;
  int pad[14];
};

__device__ inline unsigned int fkey(float f) {
  unsigned int b = __float_as_uint(f);
  return (b & 0x80000000u) ? ~b : (b | 0x80000000u);
}

// ---------------- GEMM v10: gemm5 wave structure + half-chunk weight staging (36.5KB LDS -> 4 blocks/CU) ----------------
// grid (119, 8), block 256 = 4 waves. wave0: fp64 diff 9ch; wave1: cls 18ch; wave2/3: bb 18ch each.
// Each lane owns 2 positions. Weights for 64 k staged at s=0 and s=2 inside the barrier window.
// Block (0,0) zeroes hist+ctrl+rank (replaces memset node).
__global__ __launch_bounds__(256) void gemm10(const float* __restrict__ feat,
                                              const float* __restrict__ wcls,
                                              const float* __restrict__ wbb,
                                              double* __restrict__ diffPart,
                                              float* __restrict__ clsPart,
                                              float* __restrict__ bbPart,
                                              int* __restrict__ zbase) {
  __shared__ __align__(16) float  fS[KSTEP * MTILE];   // 16 KB, [kk][p ^ swz]
  __shared__ __align__(16) float  wL[WHALF * 60];      // 15.4 KB: [k]: cls 0..17 | bb0 @20..37 | bb1 @40..57
  __shared__ __align__(16) double wDL[WHALF * 10];     // 5.1 KB: fp64 diff weights 0..8
  const int t = threadIdx.x;
  const int lane = t & 63;
  const int wv   = t >> 6;          // 0..3
  const int P0 = blockIdx.x * MTILE;
  const int k0 = blockIdx.y * KCH;

  if (blockIdx.x == 0 && blockIdx.y == 0) {
    for (int i = t; i < ZWORDS; i += 256) zbase[i] = 0;
  }

  auto STAGEW = [&](int half) {
    const int kb = k0 + half * WHALF;
    for (int idx = t; idx < WHALF * NCLS; idx += 256) {        // 1152
      int k = idx / NCLS, c = idx % NCLS;
      wL[k * 60 + c] = wcls[(size_t)(kb + k) * NCLS + c];
    }
    for (int idx = t; idx < WHALF * NBB; idx += 256) {         // 2304
      int k = idx / NBB, c = idx % NBB;
      wL[k * 60 + ((c < 18) ? (20 + c) : (40 + (c - 18)))] = wbb[(size_t)(kb + k) * NBB + c];
    }
    for (int idx = t; idx < WHALF * 9; idx += 256) {           // 576
      int k = idx / 9, j = idx % 9;
      int cC = 9 + j, cD = cC ^ 1;
      wDL[k * 10 + j] = (double)wcls[(size_t)(kb + k) * NCLS + cC] -
                        (double)wcls[(size_t)(kb + k) * NCLS + cD];
    }
  };

  double accd[2][9];
  float  accf[2][18];
#pragma unroll
  for (int p = 0; p < 2; ++p) {
#pragma unroll
    for (int j = 0; j < 9; ++j) accd[p][j] = 0.0;
#pragma unroll
    for (int c = 0; c < 18; ++c) accf[p][c] = 0.f;
  }

  float4 fr[4];
  auto LOADF = [&](int kb) {
#pragma unroll
    for (int j = 0; j < 4; ++j) {
      int idx = j * 256 + t;        // p = idx>>3 (0..127), q = idx&7
      int p = idx >> 3, q = idx & 7;
      int gp = P0 + p;
      fr[j] = make_float4(0.f, 0.f, 0.f, 0.f);
      if (gp < NPOS) fr[j] = *(const float4*)(feat + (size_t)gp * KDIM + kb + q * 4);
    }
  };
  auto WRITEF = [&]() {
#pragma unroll
    for (int j = 0; j < 4; ++j) {
      int idx = j * 256 + t;
      int p = idx >> 3, q = idx & 7;
      const float vv[4] = {fr[j].x, fr[j].y, fr[j].z, fr[j].w};
#pragma unroll
      for (int i = 0; i < 4; ++i) {
        int kk = q * 4 + i;
        int swz = ((kk >> 2) & 7) << 2;
        fS[kk * MTILE + (p ^ swz)] = vv[i];
      }
    }
  };

  LOADF(k0);
  const int NSTEP = KCH / KSTEP;    // 4 (steps 0,1 use half 0; steps 2,3 use half 1)
  for (int s = 0; s < NSTEP; ++s) {
    __syncthreads();                 // prev step's readers done before overwrite
    WRITEF();
    if ((s & 1) == 0) STAGEW(s >> 1);                  // stage weights for this half
    if (s + 1 < NSTEP) LOADF(k0 + (s + 1) * KSTEP);    // prefetch next feat tile into regs
    __syncthreads();

    const int lb = (s & 1) * KSTEP;  // local k base within the staged half (0 or 32)
    if (wv == 0) {
#pragma unroll 4
      for (int kk = 0; kk < KSTEP; ++kk) {
        int swz = ((kk >> 2) & 7) << 2;
        const float2 f2 = *(const float2*)&fS[kk * MTILE + ((lane * 2) ^ swz)];
        double f0 = (double)f2.x, f1 = (double)f2.y;
        const double* wd = &wDL[(lb + kk) * 10];       // wave-uniform -> LDS broadcast
        const double2 w01 = *(const double2*)&wd[0];
        const double2 w23 = *(const double2*)&wd[2];
        const double2 w45 = *(const double2*)&wd[4];
        const double2 w67 = *(const double2*)&wd[6];
        const double  w8  = wd[8];
        const double w[9] = {w01.x, w01.y, w23.x, w23.y, w45.x, w45.y, w67.x, w67.y, w8};
#pragma unroll
        for (int j = 0; j < 9; ++j) {
          accd[0][j] += f0 * w[j];
          accd[1][j] += f1 * w[j];
        }
      }
    } else {
      const int cb = (wv == 1) ? 0 : ((wv == 2) ? 20 : 40);
#pragma unroll 4
      for (int kk = 0; kk < KSTEP; ++kk) {
        int swz = ((kk >> 2) & 7) << 2;
        const float2 f2 = *(const float2*)&fS[kk * MTILE + ((lane * 2) ^ swz)];
        float f0 = f2.x, f1 = f2.y;
        const float* wp = &wL[(lb + kk) * 60 + cb];    // wave-uniform -> LDS broadcast
        const float4 w0 = *(const float4*)&wp[0];
        const float4 w1 = *(const float4*)&wp[4];
        const float4 w2 = *(const float4*)&wp[8];
        const float4 w3 = *(const float4*)&wp[12];
        const float2 w4 = *(const float2*)&wp[16];
        const float w[18] = {w0.x, w0.y, w0.z, w0.w, w1.x, w1.y, w1.z, w1.w,
                             w2.x, w2.y, w2.z, w2.w, w3.x, w3.y, w3.z, w3.w,
                             w4.x, w4.y};
#pragma unroll
        for (int c = 0; c < 18; ++c) {
          accf[0][c] += f0 * w[c];
          accf[1][c] += f1 * w[c];
        }
      }
    }
  }

#pragma unroll
  for (int i = 0; i < 2; ++i) {
    int gp = P0 + lane * 2 + i;
    if (gp >= NPOS) continue;
    if (wv == 0) {
      double* o = diffPart + ((size_t)blockIdx.y * NPOS + gp) * 9;
#pragma unroll
      for (int j = 0; j < 9; ++j) o[j] = accd[i][j];
    } else if (wv == 1) {
      float* o = clsPart + ((size_t)blockIdx.y * NPOS + gp) * NCLS;
#pragma unroll
      for (int c = 0; c < 18; ++c) o[c] = accf[i][c];
    } else {
      float* o = bbPart + ((size_t)blockIdx.y * NPOS + gp) * NBB + (wv - 2) * 18;
#pragma unroll
      for (int c = 0; c < 18; ++c) o[c] = accf[i][c];
    }
  }
}

// ---------------- epilogue: per-anchor outputs + fp64 sort keys + boxes + LDS histogram ----------------
__global__ __launch_bounds__(256) void epilogue(const double* __restrict__ diffPart, const float* __restrict__ clsPart,
                         const float* __restrict__ bbPart,
                         const float* __restrict__ bcls, const float* __restrict__ bbb,
                         const float* __restrict__ anchors, const float* __restrict__ imgsz,
                         float* __restrict__ out, double* __restrict__ dkeys,
                         float* __restrict__ bx0, float* __restrict__ by0,
                         float* __restrict__ bx1, float* __restrict__ by1,
                         float* __restrict__ bar, int* __restrict__ hist) {
  __shared__ int hS[HBINS];   // 32 KB per-block histogram
  const int t = threadIdx.x;
  for (int i = t; i < HBINS; i += 256) hS[i] = 0;
  __syncthreads();

  int n = blockIdx.x * 256 + t;
  if (n < NANCH) {
    int pos = n / 9, j = n % 9;
    int cA = 2 * j, cB = 2 * j + 1, cC = 9 + j, cD = cC ^ 1;
    float sA = bcls[cA], sB = bcls[cB];
#pragma unroll
    for (int ks = 0; ks < KS; ++ks) {
      const float* pp = clsPart + ((size_t)ks * NPOS + pos) * NCLS;
      sA += pp[cA]; sB += pp[cB];
    }
    double d = (double)bcls[cC] - (double)bcls[cD];
#pragma unroll
    for (int ks = 0; ks < KS; ++ks)
      d += diffPart[((size_t)ks * NPOS + pos) * 9 + j];

    out[OFF_CLSPROB + (size_t)pos * 18 + cA] = 1.0f / (1.0f + expf(sB - sA));
    out[OFF_CLSPROB + (size_t)pos * 18 + cB] = 1.0f / (1.0f + expf(sA - sB));
    out[OFF_CLSPRED + n] = (sB > sA) ? 1.0f : 0.0f;
    dkeys[n] = d;
    atomicAdd(&hS[fkey((float)d) >> 19], 1);

    float tb[4];
#pragma unroll
    for (int m = 0; m < 4; ++m) {
      float s = bbb[4 * j + m];
#pragma unroll
      for (int ks = 0; ks < KS; ++ks)
        s += bbPart[((size_t)ks * NPOS + pos) * NBB + 4 * j + m];
      tb[m] = s;
      out[OFF_BB + (size_t)n * 4 + m] = s;
    }
    float4 a = *(const float4*)(anchors + (size_t)n * 4);
    float w = a.w - a.y + 1.0f;
    float h = a.z - a.x + 1.0f;
    float x = a.x + 0.5f * h;
    float y = a.y + 0.5f * w;
    float xp = tb[0] * h + x;
    float yp = tb[1] * w + y;
    float wp = expf(tb[2]) * w;
    float hp = expf(tb[3]) * h;
    float X0 = fmaxf(xp - 0.5f * hp, 0.f);
    float X1 = fminf(xp + 0.5f * hp, imgsz[0]);
    float Y0 = fmaxf(yp - 0.5f * wp, 0.f);
    float Y1 = fminf(yp + 0.5f * wp, imgsz[1]);
    bx0[n] = X0; by0[n] = Y0; bx1[n] = X1; by1[n] = Y1;
    bar[n] = (X1 - X0) * (Y1 - Y0);
  }

  __syncthreads();
  for (int i = t; i < HBINS; i += 256) {
    int v = hS[i];
    if (v) atomicAdd(&hist[i], v);
  }
}

// ---------------- scank v2: parallel suffix-scan ----------------
__global__ __launch_bounds__(256) void scank(const int* __restrict__ hist, Ctrl* __restrict__ ctrl) {
  __shared__ int hS[HBINS];
  __shared__ int sufS[256];
  const int t = threadIdx.x;
  for (int i = t; i < HBINS; i += 256) hS[i] = hist[i];
  __syncthreads();
  int s = 0;
#pragma unroll
  for (int b = 0; b < 32; ++b) s += hS[t * 32 + b];
  sufS[t] = s;
  __syncthreads();
  for (int off = 1; off < 256; off <<= 1) {
    int v = (t + off < 256) ? sufS[t + off] : 0;
    __syncthreads();
    sufS[t] += v;
    __syncthreads();
  }
  int Ftop = (t + 1 < 256) ? sufS[t + 1] : 0;
  int Fbot = sufS[t];
  if (Ftop < TARGET_SEL && Fbot >= TARGET_SEL) {
    int acc = Ftop;
    int bstar = t * 32;
    for (int b = t * 32 + 31; b >= t * 32; --b) {
      int h = hS[b];
      if (acc + h > MCAP) { bstar = b + 1; break; }
      acc += h;
      if (acc >= TARGET_SEL) { bstar = b; break; }
    }
    ctrl->bstar = bstar;
  }
}

// ---------------- compact: block-aggregated slot assignment (1 atomic/block) ----------------
__global__ __launch_bounds__(256) void compactk(const double* __restrict__ dkeys, Ctrl* __restrict__ ctrl,
                                                int* __restrict__ sel) {
  __shared__ int wofs[4];
  __shared__ int base;
  const int t = threadIdx.x;
  const int lane = t & 63, wv = t >> 6;
  int n = blockIdx.x * 256 + t;
  bool pick = false;
  if (n < NANCH) {
    unsigned int u = fkey((float)dkeys[n]);
    pick = ((int)(u >> 19) >= ctrl->bstar);
  }
  u64 b = __ballot(pick);
  int wpre = __popcll(b & ((lane == 0) ? 0ull : (~0ull >> (64 - lane))));
  if (lane == 0) wofs[wv] = __popcll(b);
  __syncthreads();
  if (t == 0) {
    int c0 = wofs[0], c1 = wofs[1], c2 = wofs[2], c3 = wofs[3];
    int tot = c0 + c1 + c2 + c3;
    wofs[0] = 0; wofs[1] = c0; wofs[2] = c0 + c1; wofs[3] = c0 + c1 + c2;
    base = tot ? atomicAdd(&ctrl->selCount, tot) : 0;
  }
  __syncthreads();
  if (pick) {
    int slot = base + wofs[wv] + wpre;
    if (slot < MCAP) sel[slot] = n;
  }
}

// ---------------- rank by counting ----------------
__global__ __launch_bounds__(256) void rankk(const double* __restrict__ dkeys,
                                             const int* __restrict__ sel,
                                             const Ctrl* __restrict__ ctrl,
                                             int* __restrict__ rank) {
  int C = ctrl->selCount; if (C > MCAP) C = MCAP;
  if ((int)(blockIdx.x << 8) >= C || (int)(blockIdx.y << 8) >= C) return;
  __shared__ double kS[256];
  __shared__ int    iS[256];
  const int t = threadIdx.x;
  int j = blockIdx.y * 256 + t;
  if (j < C) { int n = sel[j]; kS[t] = dkeys[n]; iS[t] = n; }
  else       { kS[t] = -1.0e300; iS[t] = NANCH + j; }
  int i = blockIdx.x * 256 + t;
  double ki; int ii;
  if (i < C) { int n = sel[i]; ki = dkeys[n]; ii = n; }
  else       { ki = -1.0e300; ii = NANCH + i; }
  __syncthreads();
  int cnt = 0;
#pragma unroll 8
  for (int q = 0; q < 256; ++q) {
    double kq = kS[q]; int iq = iS[q];
    cnt += (int)((kq > ki) || (kq == ki && iq < ii));
  }
  atomicAdd(&rank[i], cnt);
}

// ---------------- scatter into sorted order ----------------
__global__ __launch_bounds__(256) void scatterk(const int* __restrict__ sel,
                                                const Ctrl* __restrict__ ctrl,
                                                const int* __restrict__ rank,
                                                int* __restrict__ sidx,
                                                float* __restrict__ sx0, float* __restrict__ sy0,
                                                float* __restrict__ sx1, float* __restrict__ sy1,
                                                float* __restrict__ sar,
                                                const float* __restrict__ bx0, const float* __restrict__ by0,
                                                const float* __restrict__ bx1, const float* __restrict__ by1,
                                                const float* __restrict__ bar) {
  int i = blockIdx.x * 256 + threadIdx.x;
  if (i >= MCAP) return;
  int C = ctrl->selCount;
  if (C > MCAP) C = MCAP;
  if (i < C) {
    int r = rank[i];
    if (r < 0 || r >= MCAP) return;       // defensive
    int n = sel[i];
    sidx[r] = n;
    sx0[r] = bx0[n]; sy0[r] = by0[n]; sx1[r] = bx1[n]; sy1[r] = by1[n]; sar[r] = bar[n];
  } else {
    sidx[i] = 0x7FFFFFFF;
    sx0[i] = 0.f; sy0[i] = 0.f; sx1[i] = 0.f; sy1[i] = 0.f; sar[i] = 0.f;
  }
}

// ---------------- IoU suppression bitmask: NROW x NROW bits ----------------
__global__ __launch_bounds__(256) void iouk2(const float* __restrict__ sx0, const float* __restrict__ sy0,
                                             const float* __restrict__ sx1, const float* __restrict__ sy1,
                                             const float* __restrict__ sar,
                                             u64* __restrict__ mask) {
  __shared__ float X0[NROW], Y0[NROW], X1[NROW], Y1[NROW], AR[NROW];   // 40 KB
  int t = threadIdx.x;
  for (int i = t; i < NROW; i += 256) {
    X0[i] = sx0[i]; Y0[i] = sy0[i]; X1[i] = sx1[i]; Y1[i] = sy1[i]; AR[i] = sar[i];
  }
  __syncthreads();
  int r0 = blockIdx.x * 16;
  for (int task = t; task < 16 * NWRD; task += 256) {
    int r = r0 + (task >> 5);
    int w = task & 31;
    float x0r = X0[r], y0r = Y0[r], x1r = X1[r], y1r = Y1[r], arr = AR[r];
    u64 bits = 0ull;
#pragma unroll 16
    for (int jj = 0; jj < 64; ++jj) {
      int jc = (w << 6) + jj;
      float iw = fminf(x1r, X1[jc]) - fmaxf(x0r, X0[jc]);
      iw = fmaxf(iw, 0.f);
      float ih = fminf(y1r, Y1[jc]) - fmaxf(y0r, Y0[jc]);
      ih = fmaxf(ih, 0.f);
      float inter = iw * ih;
      float iou = inter / (AR[jc] + arr - inter + 1e-9f);
      bits |= ((u64)(iou >= 0.7f)) << jj;
    }
    mask[(size_t)r * NWRD + w] = bits;
  }
}

// ---------------- window-parallel greedy NMS (1 wave) + final outputs ----------------
__global__ __launch_bounds__(64) void nmsk2(const u64* __restrict__ mask,
                                            const int* __restrict__ sidx,
                                            const float* __restrict__ sx0, const float* __restrict__ sy0,
                                            const float* __restrict__ sx1, const float* __restrict__ sy1,
                                            const float* __restrict__ sar,
                                            const Ctrl* __restrict__ ctrl,
                                            float* __restrict__ out) {
  __shared__ int keptPos[KSEL];
  const int lane = threadIdx.x;
  const int h = lane >> 5, m = lane & 31;
  int C = ctrl->selCount; if (C > MCAP) C = MCAP;
  int kept = 0;
  u64 sup = 0;
  const int nwin = min((C + 63) >> 6, NROW >> 6);

  u64 bufA[32], bufB[32], dgA = 0, dgB = 0;

  auto ISSUE = [&](u64* buf, u64& dg, int w) {
    const u64* base = mask + ((size_t)(w * 64 + h * 32) * NWRD + m);
#pragma unroll
    for (int j = 0; j < 32; ++j) buf[j] = base[(size_t)j * NWRD];
    dg = mask[((size_t)(w * 64 + lane)) * NWRD + w];
  };

  auto PROCW = [&](u64* buf, u64 dg, int w) {
    u64 swin = __shfl(sup, w);
    int rem = C - w * 64;
    u64 vmask = (rem >= 64) ? ~0ull : ((1ull << rem) - 1);
    u64 cand = (~swin) & vmask;
    u64 keep = 0;
    if (cand) {
      u64 gt = (lane == 63) ? 0ull : (~0ull << (lane + 1));
      bool own = (cand >> lane) & 1;
      u64 bad = __ballot(own && ((dg & cand & gt) != 0ull));
      if (bad == 0ull) {
        keep = cand;
      } else {
        u64 cur = cand;
        for (int j = 0; j < 64; ++j) {
          if ((cur >> j) & 1) {
            keep |= 1ull << j;
            u64 dj = __shfl(dg, j);
            u64 gtj = (j == 63) ? 0ull : (~0ull << (j + 1));
            cur &= ~(dj & gtj);
          }
        }
      }
    }
    int pc = __popcll(keep);
    int need = KSEL - kept;
    while (pc > need) { keep &= ~(1ull << (63 - __clzll(keep))); --pc; }
    if ((keep >> lane) & 1) {
      int p = kept + __popcll(keep & ((1ull << lane) - 1ull));
      keptPos[p] = w * 64 + lane;
    }
    u64 orv = 0;
    u64 kmh = h ? (keep >> 32) : (keep & 0xffffffffull);
#pragma unroll
    for (int j = 0; j < 32; ++j)
      if ((kmh >> j) & 1) orv |= buf[j];
    orv |= __shfl_xor(orv, 32);
    sup |= orv;
    kept += pc;
  };

  if (nwin > 0) {
    ISSUE(bufA, dgA, 0);
    int w = 0;
    while (w < nwin && kept < KSEL) {
      if (w + 1 < nwin) ISSUE(bufB, dgB, w + 1);
      PROCW(bufA, dgA, w); ++w;
      if (w >= nwin || kept >= KSEL) break;
      if (w + 1 < nwin) ISSUE(bufA, dgA, w + 1);
      PROCW(bufB, dgB, w); ++w;
    }
  }

  for (int r = NROW; r < C && kept < KSEL; ++r) {
    float x0 = sx0[r], y0 = sy0[r], x1 = sx1[r], y1 = sy1[r], ar = sar[r];
    bool supr = false;
    for (int b = lane; b < kept; b += 64) {
      int kp = keptPos[b];
      float iw = fminf(x1, sx1[kp]) - fmaxf(x0, sx0[kp]);
      iw = fmaxf(iw, 0.f);
      float ih = fminf(y1, sy1[kp]) - fmaxf(y0, sy0[kp]);
      ih = fmaxf(ih, 0.f);
      float inter = iw * ih;
      float iou = inter / (sar[kp] + ar - inter + 1e-9f);
      if (iou >= 0.7f) supr = true;
    }
    if (__ballot(supr) != 0ull) continue;
    if (lane == 0) keptPos[kept] = r;
    ++kept;
  }

  __syncthreads();
  for (int q = lane; q < KSEL; q += 64) {
    if (q < kept) {
      int kp = keptPos[q];
      int n = sidx[kp];
      out[OFF_PROP + 4 * q + 0] = sx0[kp];
      out[OFF_PROP + 4 * q + 1] = sy0[kp];
      out[OFF_PROP + 4 * q + 2] = sx1[kp];
      out[OFF_PROP + 4 * q + 3] = sy1[kp];
      out[OFF_IDX + q] = (float)n;
    } else {
      out[OFF_PROP + 4 * q + 0] = 0.f;
      out[OFF_PROP + 4 * q + 1] = 0.f;
      out[OFF_PROP + 4 * q + 2] = 0.f;
      out[OFF_PROP + 4 * q + 3] = 0.f;
      out[OFF_IDX + q] = 0.f;
    }
  }
}

// ---------------- sentinel when ws is too small (diagnosable signature) ----------------
__global__ void badws(float* out) {
  if (threadIdx.x == 0 && blockIdx.x == 0) out[0] = 1.0e8f;
}

extern "C" void kernel_launch(void* const* d_in, const int* in_sizes, int n_in,
                              void* d_out, int out_size, void* d_ws, size_t ws_size,
                              hipStream_t stream) {
  (void)in_sizes; (void)n_in; (void)out_size;
  const float* feat    = (const float*)d_in[0];
  const float* anchors = (const float*)d_in[1];
  const float* imgsz   = (const float*)d_in[2];
  const float* wcls    = (const float*)d_in[3];
  const float* bcls    = (const float*)d_in[4];
  const float* wbb     = (const float*)d_in[5];
  const float* bbb     = (const float*)d_in[6];
  float* out = (float*)d_out;
  char* ws = (char*)d_ws;

  const size_t o_diff   = 0;
  const size_t o_cls    = o_diff + (size_t)KS * NPOS * 9 * 8;
  const size_t o_bb     = o_cls + (size_t)KS * NPOS * NCLS * 4;
  const size_t o_dkeys  = o_bb + (size_t)KS * NPOS * NBB * 4;
  const size_t o_bx0    = o_dkeys + (size_t)NANCH * 8;
  const size_t o_by0    = o_bx0 + (size_t)NANCH * 4;
  const size_t o_bx1    = o_by0 + (size_t)NANCH * 4;
  const size_t o_by1    = o_bx1 + (size_t)NANCH * 4;
  const size_t o_bar    = o_by1 + (size_t)NANCH * 4;
  const size_t o_hist   = o_bar + (size_t)NANCH * 4;
  const size_t o_ctrl   = o_hist + (size_t)HBINS * 4;
  const size_t o_rank   = o_ctrl + 256;
  const size_t o_sel    = o_rank + (size_t)MCAP * 4;
  const size_t o_sidx   = o_sel + (size_t)MCAP * 4;
  const size_t o_sx0    = o_sidx + (size_t)MCAP * 4;
  const size_t o_sy0    = o_sx0 + (size_t)MCAP * 4;
  const size_t o_sx1    = o_sy0 + (size_t)MCAP * 4;
  const size_t o_sy1    = o_sx1 + (size_t)MCAP * 4;
  const size_t o_sar    = o_sy1 + (size_t)MCAP * 4;
  const size_t o_mask   = o_sar + (size_t)MCAP * 4;
  const size_t need     = o_mask + (size_t)NROW * NWRD * 8;

  if (ws_size < need) {
    badws<<<dim3(1), dim3(64), 0, stream>>>(out);
    return;
  }

  double* diffPart = (double*)(ws + o_diff);
  float*  clsPart  = (float*)(ws + o_cls);
  float*  bbPart   = (float*)(ws + o_bb);
  double* dkeys    = (double*)(ws + o_dkeys);
  float*  bx0      = (float*)(ws + o_bx0);
  float*  by0      = (float*)(ws + o_by0);
  float*  bx1      = (float*)(ws + o_bx1);
  float*  by1      = (float*)(ws + o_by1);
  float*  bar      = (float*)(ws + o_bar);
  int*    hist     = (int*)(ws + o_hist);
  Ctrl*   ctrl     = (Ctrl*)(ws + o_ctrl);
  int*    rank     = (int*)(ws + o_rank);
  int*    sel      = (int*)(ws + o_sel);
  int*    sidx     = (int*)(ws + o_sidx);
  float*  sx0      = (float*)(ws + o_sx0);
  float*  sy0      = (float*)(ws + o_sy0);
  float*  sx1      = (float*)(ws + o_sx1);
  float*  sy1      = (float*)(ws + o_sy1);
  float*  sar      = (float*)(ws + o_sar);
  u64*    mask     = (u64*)(ws + o_mask);

  // hist+ctrl+rank zeroed inside gemm10 (block 0,0) — no memset node needed.
  gemm10<<<dim3((NPOS + MTILE - 1) / MTILE, KS), dim3(256), 0, stream>>>(
      feat, wcls, wbb, diffPart, clsPart, bbPart, (int*)(ws + o_hist));
  epilogue<<<dim3((NANCH + 255) / 256), dim3(256), 0, stream>>>(
      diffPart, clsPart, bbPart, bcls, bbb, anchors, imgsz, out, dkeys, bx0, by0, bx1, by1, bar, hist);
  scank<<<dim3(1), dim3(256), 0, stream>>>(hist, ctrl);
  compactk<<<dim3((NANCH + 255) / 256), dim3(256), 0, stream>>>(dkeys, ctrl, sel);
  rankk<<<dim3(MCAP / 256, MCAP / 256), dim3(256), 0, stream>>>(dkeys, sel, ctrl, rank);
  scatterk<<<dim3(MCAP / 256), dim3(256), 0, stream>>>(sel, ctrl, rank, sidx,
                                                       sx0, sy0, sx1, sy1, sar,
                                                       bx0, by0, bx1, by1, bar);
  iouk2<<<dim3(NROW / 16), dim3(256), 0, stream>>>(sx0, sy0, sx1, sy1, sar, mask);
  nmsk2<<<dim3(1), dim3(64), 0, stream>>>(mask, sidx, sx0, sy0, sx1, sy1, sar, ctrl, out);
}

// Round 17
// 159.698 us; speedup vs baseline: 1.1076x; 1.1076x over previous
//
#include <hip/hip_runtime.h>
#include <cstdint>
#include <cstddef>

#define NPOS   15200
#define NANCH  136800
#define KDIM   1024
#define NCLS   18
#define NBB    36
#define KS     8
#define KCH    (KDIM / KS)        // 128 k per split
#define KSTEP  32
#define MTILE  256
#define MCAP   4096
#define NROW   2048               // NMS mask rows (processing depth cap; fallback beyond)
#define NWRD   32                 // mask words per row (2048 cols)
#define TARGET_SEL 3072
#define KSEL   1000
#define HBINS  8192
#define ZWORDS ((HBINS * 4 + 256 + MCAP * 4) / 4)

typedef unsigned long long u64;

// out layout (floats): proposals[1000*4] | idx[1000] | cls_prob[273600] | cls_pred[136800] | bbox_pred[547200]
#define OFF_PROP    0
#define OFF_IDX     4000
#define OFF_CLSPROB 5000
#define OFF_CLSPRED 278600
#define OFF_BB      415400

struct Ctrl {
  int selCount;
  int bstar;
  int pad[14];
};

__device__ inline unsigned int fkey(float f) {
  unsigned int b = __float_as_uint(f);
  return (b & 0x80000000u) ? ~b : (b | 0x80000000u);
}

// ---------------- GEMM v6 (round-14 best): 4 pos/lane, weights staged once, KS=8 ----------------
// grid (60, 8), block 256 = 4 waves. wave0: fp64 diff 9ch; wave1: cls 18ch; wave2/3: bb 18ch each.
// Block (0,0) additionally zeroes hist+ctrl+rank (replaces the memset node).
__global__ __launch_bounds__(256) void gemm6(const float* __restrict__ feat,
                                             const float* __restrict__ wcls,
                                             const float* __restrict__ wbb,
                                             double* __restrict__ diffPart,
                                             float* __restrict__ clsPart,
                                             float* __restrict__ bbPart,
                                             int* __restrict__ zbase) {
  __shared__ __align__(16) float  fS[KSTEP * MTILE];   // 32 KB, [kk][p ^ swz]
  __shared__ __align__(16) float  wL[KCH * 72];        // 36.9 KB
  __shared__ __align__(16) double wDL[KCH * 10];       // 10.2 KB
  const int t = threadIdx.x;
  const int lane = t & 63;
  const int wv   = t >> 6;          // 0..3
  const int P0 = blockIdx.x * MTILE;
  const int k0 = blockIdx.y * KCH;

  if (blockIdx.x == 0 && blockIdx.y == 0) {
    for (int i = t; i < ZWORDS; i += 256) zbase[i] = 0;
  }

  for (int idx = t; idx < KCH * NCLS; idx += 256) {
    int k = idx / NCLS, c = idx % NCLS;
    wL[k * 72 + c] = wcls[(size_t)(k0 + k) * NCLS + c];
  }
  for (int idx = t; idx < KCH * NBB; idx += 256) {
    int k = idx / NBB, c = idx % NBB;
    wL[k * 72 + ((c < 18) ? (24 + c) : (48 + (c - 18)))] = wbb[(size_t)(k0 + k) * NBB + c];
  }
  for (int idx = t; idx < KCH * 9; idx += 256) {
    int k = idx / 9, j = idx % 9;
    int cC = 9 + j, cD = cC ^ 1;
    wDL[k * 10 + j] = (double)wcls[(size_t)(k0 + k) * NCLS + cC] -
                      (double)wcls[(size_t)(k0 + k) * NCLS + cD];
  }

  double accd[4][9];
  float  accf[4][18];
#pragma unroll
  for (int p = 0; p < 4; ++p) {
#pragma unroll
    for (int j = 0; j < 9; ++j) accd[p][j] = 0.0;
#pragma unroll
    for (int c = 0; c < 18; ++c) accf[p][c] = 0.f;
  }

  float4 fr[8];
  auto LOADF = [&](int kb) {
#pragma unroll
    for (int j = 0; j < 8; ++j) {
      int idx = j * 256 + t;        // p = idx>>3 (0..255), q = idx&7
      int p = idx >> 3, q = idx & 7;
      int gp = P0 + p;
      fr[j] = make_float4(0.f, 0.f, 0.f, 0.f);
      if (gp < NPOS) fr[j] = *(const float4*)(feat + (size_t)gp * KDIM + kb + q * 4);
    }
  };
  auto WRITEF = [&]() {
#pragma unroll
    for (int j = 0; j < 8; ++j) {
      int idx = j * 256 + t;
      int p = idx >> 3, q = idx & 7;
      const float vv[4] = {fr[j].x, fr[j].y, fr[j].z, fr[j].w};
#pragma unroll
      for (int i = 0; i < 4; ++i) {
        int kk = q * 4 + i;
        int swz = ((kk >> 2) & 7) << 2;
        fS[kk * MTILE + (p ^ swz)] = vv[i];
      }
    }
  };

  LOADF(k0);
  const int NSTEP = KCH / KSTEP;    // 4
  for (int s = 0; s < NSTEP; ++s) {
    __syncthreads();
    WRITEF();
    if (s + 1 < NSTEP) LOADF(k0 + (s + 1) * KSTEP);
    __syncthreads();

    const int kb = s * KSTEP;
    if (wv == 0) {
#pragma unroll 2
      for (int kk = 0; kk < KSTEP; ++kk) {
        int swz = ((kk >> 2) & 7) << 2;
        const float4 f4 = *(const float4*)&fS[kk * MTILE + ((lane * 4) ^ swz)];
        const double f[4] = {(double)f4.x, (double)f4.y, (double)f4.z, (double)f4.w};
        const double* wd = &wDL[(kb + kk) * 10];       // wave-uniform -> LDS broadcast
        const double2 w01 = *(const double2*)&wd[0];
        const double2 w23 = *(const double2*)&wd[2];
        const double2 w45 = *(const double2*)&wd[4];
        const double2 w67 = *(const double2*)&wd[6];
        const double  w8  = wd[8];
        const double w[9] = {w01.x, w01.y, w23.x, w23.y, w45.x, w45.y, w67.x, w67.y, w8};
#pragma unroll
        for (int p = 0; p < 4; ++p)
#pragma unroll
          for (int j = 0; j < 9; ++j) accd[p][j] += f[p] * w[j];
      }
    } else {
      const int cb = (wv == 1) ? 0 : ((wv == 2) ? 24 : 48);
#pragma unroll 2
      for (int kk = 0; kk < KSTEP; ++kk) {
        int swz = ((kk >> 2) & 7) << 2;
        const float4 f4 = *(const float4*)&fS[kk * MTILE + ((lane * 4) ^ swz)];
        const float f[4] = {f4.x, f4.y, f4.z, f4.w};
        const float* wp = &wL[(kb + kk) * 72 + cb];    // wave-uniform -> LDS broadcast
        const float4 w0 = *(const float4*)&wp[0];
        const float4 w1 = *(const float4*)&wp[4];
        const float4 w2 = *(const float4*)&wp[8];
        const float4 w3 = *(const float4*)&wp[12];
        const float2 w4 = *(const float2*)&wp[16];
        const float w[18] = {w0.x, w0.y, w0.z, w0.w, w1.x, w1.y, w1.z, w1.w,
                             w2.x, w2.y, w2.z, w2.w, w3.x, w3.y, w3.z, w3.w,
                             w4.x, w4.y};
#pragma unroll
        for (int p = 0; p < 4; ++p)
#pragma unroll
          for (int c = 0; c < 18; ++c) accf[p][c] += f[p] * w[c];
      }
    }
  }

#pragma unroll
  for (int i = 0; i < 4; ++i) {
    int gp = P0 + lane * 4 + i;
    if (gp >= NPOS) continue;
    if (wv == 0) {
      double* o = diffPart + ((size_t)blockIdx.y * NPOS + gp) * 9;
#pragma unroll
      for (int j = 0; j < 9; ++j) o[j] = accd[i][j];
    } else if (wv == 1) {
      float* o = clsPart + ((size_t)blockIdx.y * NPOS + gp) * NCLS;
#pragma unroll
      for (int c = 0; c < 18; ++c) o[c] = accf[i][c];
    } else {
      float* o = bbPart + ((size_t)blockIdx.y * NPOS + gp) * NBB + (wv - 2) * 18;
#pragma unroll
      for (int c = 0; c < 18; ++c) o[c] = accf[i][c];
    }
  }
}

// ---------------- epilogue: per-anchor outputs + fp64 sort keys + boxes + LDS histogram ----------------
__global__ __launch_bounds__(256) void epilogue(const double* __restrict__ diffPart, const float* __restrict__ clsPart,
                         const float* __restrict__ bbPart,
                         const float* __restrict__ bcls, const float* __restrict__ bbb,
                         const float* __restrict__ anchors, const float* __restrict__ imgsz,
                         float* __restrict__ out, double* __restrict__ dkeys,
                         float* __restrict__ bx0, float* __restrict__ by0,
                         float* __restrict__ bx1, float* __restrict__ by1,
                         float* __restrict__ bar, int* __restrict__ hist) {
  __shared__ int hS[HBINS];   // 32 KB per-block histogram
  const int t = threadIdx.x;
  for (int i = t; i < HBINS; i += 256) hS[i] = 0;
  __syncthreads();

  int n = blockIdx.x * 256 + t;
  if (n < NANCH) {
    int pos = n / 9, j = n % 9;
    int cA = 2 * j, cB = 2 * j + 1, cC = 9 + j, cD = cC ^ 1;
    float sA = bcls[cA], sB = bcls[cB];
#pragma unroll
    for (int ks = 0; ks < KS; ++ks) {
      const float* pp = clsPart + ((size_t)ks * NPOS + pos) * NCLS;
      sA += pp[cA]; sB += pp[cB];
    }
    double d = (double)bcls[cC] - (double)bcls[cD];
#pragma unroll
    for (int ks = 0; ks < KS; ++ks)
      d += diffPart[((size_t)ks * NPOS + pos) * 9 + j];

    out[OFF_CLSPROB + (size_t)pos * 18 + cA] = 1.0f / (1.0f + expf(sB - sA));
    out[OFF_CLSPROB + (size_t)pos * 18 + cB] = 1.0f / (1.0f + expf(sA - sB));
    out[OFF_CLSPRED + n] = (sB > sA) ? 1.0f : 0.0f;
    dkeys[n] = d;
    atomicAdd(&hS[fkey((float)d) >> 19], 1);

    float tb[4];
#pragma unroll
    for (int m = 0; m < 4; ++m) {
      float s = bbb[4 * j + m];
#pragma unroll
      for (int ks = 0; ks < KS; ++ks)
        s += bbPart[((size_t)ks * NPOS + pos) * NBB + 4 * j + m];
      tb[m] = s;
      out[OFF_BB + (size_t)n * 4 + m] = s;
    }
    float4 a = *(const float4*)(anchors + (size_t)n * 4);
    float w = a.w - a.y + 1.0f;
    float h = a.z - a.x + 1.0f;
    float x = a.x + 0.5f * h;
    float y = a.y + 0.5f * w;
    float xp = tb[0] * h + x;
    float yp = tb[1] * w + y;
    float wp = expf(tb[2]) * w;
    float hp = expf(tb[3]) * h;
    float X0 = fmaxf(xp - 0.5f * hp, 0.f);
    float X1 = fminf(xp + 0.5f * hp, imgsz[0]);
    float Y0 = fmaxf(yp - 0.5f * wp, 0.f);
    float Y1 = fminf(yp + 0.5f * wp, imgsz[1]);
    bx0[n] = X0; by0[n] = Y0; bx1[n] = X1; by1[n] = Y1;
    bar[n] = (X1 - X0) * (Y1 - Y0);
  }

  __syncthreads();
  for (int i = t; i < HBINS; i += 256) {
    int v = hS[i];
    if (v) atomicAdd(&hist[i], v);
  }
}

// ---------------- scank v2: parallel suffix-scan ----------------
__global__ __launch_bounds__(256) void scank(const int* __restrict__ hist, Ctrl* __restrict__ ctrl) {
  __shared__ int hS[HBINS];
  __shared__ int sufS[256];
  const int t = threadIdx.x;
  for (int i = t; i < HBINS; i += 256) hS[i] = hist[i];
  __syncthreads();
  int s = 0;
#pragma unroll
  for (int b = 0; b < 32; ++b) s += hS[t * 32 + b];
  sufS[t] = s;
  __syncthreads();
  for (int off = 1; off < 256; off <<= 1) {
    int v = (t + off < 256) ? sufS[t + off] : 0;
    __syncthreads();
    sufS[t] += v;
    __syncthreads();
  }
  int Ftop = (t + 1 < 256) ? sufS[t + 1] : 0;
  int Fbot = sufS[t];
  if (Ftop < TARGET_SEL && Fbot >= TARGET_SEL) {
    int acc = Ftop;
    int bstar = t * 32;
    for (int b = t * 32 + 31; b >= t * 32; --b) {
      int h = hS[b];
      if (acc + h > MCAP) { bstar = b + 1; break; }
      acc += h;
      if (acc >= TARGET_SEL) { bstar = b; break; }
    }
    ctrl->bstar = bstar;
  }
}

// ---------------- compact: block-aggregated slot assignment (1 atomic/block) ----------------
__global__ __launch_bounds__(256) void compactk(const double* __restrict__ dkeys, Ctrl* __restrict__ ctrl,
                                                int* __restrict__ sel) {
  __shared__ int wofs[4];
  __shared__ int base;
  const int t = threadIdx.x;
  const int lane = t & 63, wv = t >> 6;
  int n = blockIdx.x * 256 + t;
  bool pick = false;
  if (n < NANCH) {
    unsigned int u = fkey((float)dkeys[n]);
    pick = ((int)(u >> 19) >= ctrl->bstar);
  }
  u64 b = __ballot(pick);
  int wpre = __popcll(b & ((lane == 0) ? 0ull : (~0ull >> (64 - lane))));
  if (lane == 0) wofs[wv] = __popcll(b);
  __syncthreads();
  if (t == 0) {
    int c0 = wofs[0], c1 = wofs[1], c2 = wofs[2], c3 = wofs[3];
    int tot = c0 + c1 + c2 + c3;
    wofs[0] = 0; wofs[1] = c0; wofs[2] = c0 + c1; wofs[3] = c0 + c1 + c2;
    base = tot ? atomicAdd(&ctrl->selCount, tot) : 0;
  }
  __syncthreads();
  if (pick) {
    int slot = base + wofs[wv] + wpre;
    if (slot < MCAP) sel[slot] = n;
  }
}

// ---------------- rank by counting ----------------
__global__ __launch_bounds__(256) void rankk(const double* __restrict__ dkeys,
                                             const int* __restrict__ sel,
                                             const Ctrl* __restrict__ ctrl,
                                             int* __restrict__ rank) {
  int C = ctrl->selCount; if (C > MCAP) C = MCAP;
  if ((int)(blockIdx.x << 8) >= C || (int)(blockIdx.y << 8) >= C) return;
  __shared__ double kS[256];
  __shared__ int    iS[256];
  const int t = threadIdx.x;
  int j = blockIdx.y * 256 + t;
  if (j < C) { int n = sel[j]; kS[t] = dkeys[n]; iS[t] = n; }
  else       { kS[t] = -1.0e300; iS[t] = NANCH + j; }
  int i = blockIdx.x * 256 + t;
  double ki; int ii;
  if (i < C) { int n = sel[i]; ki = dkeys[n]; ii = n; }
  else       { ki = -1.0e300; ii = NANCH + i; }
  __syncthreads();
  int cnt = 0;
#pragma unroll 8
  for (int q = 0; q < 256; ++q) {
    double kq = kS[q]; int iq = iS[q];
    cnt += (int)((kq > ki) || (kq == ki && iq < ii));
  }
  atomicAdd(&rank[i], cnt);
}

// ---------------- scatter into sorted order ----------------
__global__ __launch_bounds__(256) void scatterk(const int* __restrict__ sel,
                                                const Ctrl* __restrict__ ctrl,
                                                const int* __restrict__ rank,
                                                int* __restrict__ sidx,
                                                float* __restrict__ sx0, float* __restrict__ sy0,
                                                float* __restrict__ sx1, float* __restrict__ sy1,
                                                float* __restrict__ sar,
                                                const float* __restrict__ bx0, const float* __restrict__ by0,
                                                const float* __restrict__ bx1, const float* __restrict__ by1,
                                                const float* __restrict__ bar) {
  int i = blockIdx.x * 256 + threadIdx.x;
  if (i >= MCAP) return;
  int C = ctrl->selCount;
  if (C > MCAP) C = MCAP;
  if (i < C) {
    int r = rank[i];
    if (r < 0 || r >= MCAP) return;       // defensive
    int n = sel[i];
    sidx[r] = n;
    sx0[r] = bx0[n]; sy0[r] = by0[n]; sx1[r] = bx1[n]; sy1[r] = by1[n]; sar[r] = bar[n];
  } else {
    sidx[i] = 0x7FFFFFFF;
    sx0[i] = 0.f; sy0[i] = 0.f; sx1[i] = 0.f; sy1[i] = 0.f; sar[i] = 0.f;
  }
}

// ---------------- IoU suppression bitmask: NROW x NROW bits ----------------
__global__ __launch_bounds__(256) void iouk2(const float* __restrict__ sx0, const float* __restrict__ sy0,
                                             const float* __restrict__ sx1, const float* __restrict__ sy1,
                                             const float* __restrict__ sar,
                                             u64* __restrict__ mask) {
  __shared__ float X0[NROW], Y0[NROW], X1[NROW], Y1[NROW], AR[NROW];   // 40 KB
  int t = threadIdx.x;
  for (int i = t; i < NROW; i += 256) {
    X0[i] = sx0[i]; Y0[i] = sy0[i]; X1[i] = sx1[i]; Y1[i] = sy1[i]; AR[i] = sar[i];
  }
  __syncthreads();
  int r0 = blockIdx.x * 16;
  for (int task = t; task < 16 * NWRD; task += 256) {
    int r = r0 + (task >> 5);
    int w = task & 31;
    float x0r = X0[r], y0r = Y0[r], x1r = X1[r], y1r = Y1[r], arr = AR[r];
    u64 bits = 0ull;
#pragma unroll 16
    for (int jj = 0; jj < 64; ++jj) {
      int jc = (w << 6) + jj;
      float iw = fminf(x1r, X1[jc]) - fmaxf(x0r, X0[jc]);
      iw = fmaxf(iw, 0.f);
      float ih = fminf(y1r, Y1[jc]) - fmaxf(y0r, Y0[jc]);
      ih = fmaxf(ih, 0.f);
      float inter = iw * ih;
      float iou = inter / (AR[jc] + arr - inter + 1e-9f);
      bits |= ((u64)(iou >= 0.7f)) << jj;
    }
    mask[(size_t)r * NWRD + w] = bits;
  }
}

// ---------------- window-parallel greedy NMS (1 wave) + final outputs ----------------
__global__ __launch_bounds__(64) void nmsk2(const u64* __restrict__ mask,
                                            const int* __restrict__ sidx,
                                            const float* __restrict__ sx0, const float* __restrict__ sy0,
                                            const float* __restrict__ sx1, const float* __restrict__ sy1,
                                            const float* __restrict__ sar,
                                            const Ctrl* __restrict__ ctrl,
                                            float* __restrict__ out) {
  __shared__ int keptPos[KSEL];
  const int lane = threadIdx.x;
  const int h = lane >> 5, m = lane & 31;
  int C = ctrl->selCount; if (C > MCAP) C = MCAP;
  int kept = 0;
  u64 sup = 0;
  const int nwin = min((C + 63) >> 6, NROW >> 6);

  u64 bufA[32], bufB[32], dgA = 0, dgB = 0;

  auto ISSUE = [&](u64* buf, u64& dg, int w) {
    const u64* base = mask + ((size_t)(w * 64 + h * 32) * NWRD + m);
#pragma unroll
    for (int j = 0; j < 32; ++j) buf[j] = base[(size_t)j * NWRD];
    dg = mask[((size_t)(w * 64 + lane)) * NWRD + w];
  };

  auto PROCW = [&](u64* buf, u64 dg, int w) {
    u64 swin = __shfl(sup, w);
    int rem = C - w * 64;
    u64 vmask = (rem >= 64) ? ~0ull : ((1ull << rem) - 1);
    u64 cand = (~swin) & vmask;
    u64 keep = 0;
    if (cand) {
      u64 gt = (lane == 63) ? 0ull : (~0ull << (lane + 1));
      bool own = (cand >> lane) & 1;
      u64 bad = __ballot(own && ((dg & cand & gt) != 0ull));
      if (bad == 0ull) {
        keep = cand;
      } else {
        u64 cur = cand;
        for (int j = 0; j < 64; ++j) {
          if ((cur >> j) & 1) {
            keep |= 1ull << j;
            u64 dj = __shfl(dg, j);
            u64 gtj = (j == 63) ? 0ull : (~0ull << (j + 1));
            cur &= ~(dj & gtj);
          }
        }
      }
    }
    int pc = __popcll(keep);
    int need = KSEL - kept;
    while (pc > need) { keep &= ~(1ull << (63 - __clzll(keep))); --pc; }
    if ((keep >> lane) & 1) {
      int p = kept + __popcll(keep & ((1ull << lane) - 1ull));
      keptPos[p] = w * 64 + lane;
    }
    u64 orv = 0;
    u64 kmh = h ? (keep >> 32) : (keep & 0xffffffffull);
#pragma unroll
    for (int j = 0; j < 32; ++j)
      if ((kmh >> j) & 1) orv |= buf[j];
    orv |= __shfl_xor(orv, 32);
    sup |= orv;
    kept += pc;
  };

  if (nwin > 0) {
    ISSUE(bufA, dgA, 0);
    int w = 0;
    while (w < nwin && kept < KSEL) {
      if (w + 1 < nwin) ISSUE(bufB, dgB, w + 1);
      PROCW(bufA, dgA, w); ++w;
      if (w >= nwin || kept >= KSEL) break;
      if (w + 1 < nwin) ISSUE(bufA, dgA, w + 1);
      PROCW(bufB, dgB, w); ++w;
    }
  }

  for (int r = NROW; r < C && kept < KSEL; ++r) {
    float x0 = sx0[r], y0 = sy0[r], x1 = sx1[r], y1 = sy1[r], ar = sar[r];
    bool supr = false;
    for (int b = lane; b < kept; b += 64) {
      int kp = keptPos[b];
      float iw = fminf(x1, sx1[kp]) - fmaxf(x0, sx0[kp]);
      iw = fmaxf(iw, 0.f);
      float ih = fminf(y1, sy1[kp]) - fmaxf(y0, sy0[kp]);
      ih = fmaxf(ih, 0.f);
      float inter = iw * ih;
      float iou = inter / (sar[kp] + ar - inter + 1e-9f);
      if (iou >= 0.7f) supr = true;
    }
    if (__ballot(supr) != 0ull) continue;
    if (lane == 0) keptPos[kept] = r;
    ++kept;
  }

  __syncthreads();
  for (int q = lane; q < KSEL; q += 64) {
    if (q < kept) {
      int kp = keptPos[q];
      int n = sidx[kp];
      out[OFF_PROP + 4 * q + 0] = sx0[kp];
      out[OFF_PROP + 4 * q + 1] = sy0[kp];
      out[OFF_PROP + 4 * q + 2] = sx1[kp];
      out[OFF_PROP + 4 * q + 3] = sy1[kp];
      out[OFF_IDX + q] = (float)n;
    } else {
      out[OFF_PROP + 4 * q + 0] = 0.f;
      out[OFF_PROP + 4 * q + 1] = 0.f;
      out[OFF_PROP + 4 * q + 2] = 0.f;
      out[OFF_PROP + 4 * q + 3] = 0.f;
      out[OFF_IDX + q] = 0.f;
    }
  }
}

// ---------------- sentinel when ws is too small (diagnosable signature) ----------------
__global__ void badws(float* out) {
  if (threadIdx.x == 0 && blockIdx.x == 0) out[0] = 1.0e8f;
}

extern "C" void kernel_launch(void* const* d_in, const int* in_sizes, int n_in,
                              void* d_out, int out_size, void* d_ws, size_t ws_size,
                              hipStream_t stream) {
  (void)in_sizes; (void)n_in; (void)out_size;
  const float* feat    = (const float*)d_in[0];
  const float* anchors = (const float*)d_in[1];
  const float* imgsz   = (const float*)d_in[2];
  const float* wcls    = (const float*)d_in[3];
  const float* bcls    = (const float*)d_in[4];
  const float* wbb     = (const float*)d_in[5];
  const float* bbb     = (const float*)d_in[6];
  float* out = (float*)d_out;
  char* ws = (char*)d_ws;

  const size_t o_diff   = 0;
  const size_t o_cls    = o_diff + (size_t)KS * NPOS * 9 * 8;
  const size_t o_bb     = o_cls + (size_t)KS * NPOS * NCLS * 4;
  const size_t o_dkeys  = o_bb + (size_t)KS * NPOS * NBB * 4;
  const size_t o_bx0    = o_dkeys + (size_t)NANCH * 8;
  const size_t o_by0    = o_bx0 + (size_t)NANCH * 4;
  const size_t o_bx1    = o_by0 + (size_t)NANCH * 4;
  const size_t o_by1    = o_bx1 + (size_t)NANCH * 4;
  const size_t o_bar    = o_by1 + (size_t)NANCH * 4;
  const size_t o_hist   = o_bar + (size_t)NANCH * 4;
  const size_t o_ctrl   = o_hist + (size_t)HBINS * 4;
  const size_t o_rank   = o_ctrl + 256;
  const size_t o_sel    = o_rank + (size_t)MCAP * 4;
  const size_t o_sidx   = o_sel + (size_t)MCAP * 4;
  const size_t o_sx0    = o_sidx + (size_t)MCAP * 4;
  const size_t o_sy0    = o_sx0 + (size_t)MCAP * 4;
  const size_t o_sx1    = o_sy0 + (size_t)MCAP * 4;
  const size_t o_sy1    = o_sx1 + (size_t)MCAP * 4;
  const size_t o_sar    = o_sy1 + (size_t)MCAP * 4;
  const size_t o_mask   = o_sar + (size_t)MCAP * 4;
  const size_t need     = o_mask + (size_t)NROW * NWRD * 8;

  if (ws_size < need) {
    badws<<<dim3(1), dim3(64), 0, stream>>>(out);
    return;
  }

  double* diffPart = (double*)(ws + o_diff);
  float*  clsPart  = (float*)(ws + o_cls);
  float*  bbPart   = (float*)(ws + o_bb);
  double* dkeys    = (double*)(ws + o_dkeys);
  float*  bx0      = (float*)(ws + o_bx0);
  float*  by0      = (float*)(ws + o_by0);
  float*  bx1      = (float*)(ws + o_bx1);
  float*  by1      = (float*)(ws + o_by1);
  float*  bar      = (float*)(ws + o_bar);
  int*    hist     = (int*)(ws + o_hist);
  Ctrl*   ctrl     = (Ctrl*)(ws + o_ctrl);
  int*    rank     = (int*)(ws + o_rank);
  int*    sel      = (int*)(ws + o_sel);
  int*    sidx     = (int*)(ws + o_sidx);
  float*  sx0      = (float*)(ws + o_sx0);
  float*  sy0      = (float*)(ws + o_sy0);
  float*  sx1      = (float*)(ws + o_sx1);
  float*  sy1      = (float*)(ws + o_sy1);
  float*  sar      = (float*)(ws + o_sar);
  u64*    mask     = (u64*)(ws + o_mask);

  // hist+ctrl+rank zeroed inside gemm6 (block 0,0) — no memset node needed.
  gemm6<<<dim3((NPOS + MTILE - 1) / MTILE, KS), dim3(256), 0, stream>>>(
      feat, wcls, wbb, diffPart, clsPart, bbPart, (int*)(ws + o_hist));
  epilogue<<<dim3((NANCH + 255) / 256), dim3(256), 0, stream>>>(
      diffPart, clsPart, bbPart, bcls, bbb, anchors, imgsz, out, dkeys, bx0, by0, bx1, by1, bar, hist);
  scank<<<dim3(1), dim3(256), 0, stream>>>(hist, ctrl);
  compactk<<<dim3((NANCH + 255) / 256), dim3(256), 0, stream>>>(dkeys, ctrl, sel);
  rankk<<<dim3(MCAP / 256, MCAP / 256), dim3(256), 0, stream>>>(dkeys, sel, ctrl, rank);
  scatterk<<<dim3(MCAP / 256), dim3(256), 0, stream>>>(sel, ctrl, rank, sidx,
                                                       sx0, sy0, sx1, sy1, sar,
                                                       bx0, by0, bx1, by1, bar);
  iouk2<<<dim3(NROW / 16), dim3(256), 0, stream>>>(sx0, sy0, sx1, sy1, sar, mask);
  nmsk2<<<dim3(1), dim3(64), 0, stream>>>(mask, sidx, sx0, sy0, sx1, sy1, sar, ctrl, out);
}